// Round 25
// baseline (282.775 us; speedup 1.0000x reference)
//
#include <hip/hip_runtime.h>

typedef unsigned short u16;
typedef unsigned int u32;
typedef __bf16 bf16x8 __attribute__((ext_vector_type(8)));
typedef float f32x4 __attribute__((ext_vector_type(4)));
typedef float f32x16 __attribute__((ext_vector_type(16)));
typedef int v2i __attribute__((ext_vector_type(2)));

#define S_LEN 4096
#define HDIM 2048
#define KVDIM 512
#define N_HEADS 16
#define HEAD_D 128

__device__ __forceinline__ u16 f2bf(float f) {
  u32 u = __float_as_uint(f);
  u32 r = (u + 0x7FFFu + ((u >> 16) & 1u)) >> 16;
  return (u16)r;
}
__device__ __forceinline__ float bf2f(u16 h) {
  return __uint_as_float(((u32)h) << 16);
}
__device__ __forceinline__ float exp2_fast(float x) {
  float r;
  asm("v_exp_f32 %0, %1" : "=v"(r) : "v"(x));
  return r;
}
__device__ __forceinline__ u32 cvt_pk_bf16(float lo, float hi) {
  u32 r;
  asm("v_cvt_pk_bf16_f32 %0, %1, %2" : "=v"(r) : "v"(lo), "v"(hi));
  return r;
}
__device__ __forceinline__ void gload16(const u16* g, const u16* l) {
  __builtin_amdgcn_global_load_lds(
      (const __attribute__((address_space(1))) void*)g,
      (__attribute__((address_space(3))) void*)l, 16, 0, 0);
}

// ---------------- prep: f32->bf16 cast (blocks 0..4095) + rope table (4096..5119) ----
__global__ void k_prep(const float* __restrict__ in, u16* __restrict__ out,
                       float* __restrict__ cosT, float* __restrict__ sinT) {
  int b = blockIdx.x;
  int tid = threadIdx.x;
  if (b < 4096) {
    int i = b * 256 + tid;  // S*HDIM/8 = 1048576 threads
    const float4* p = reinterpret_cast<const float4*>(in) + (size_t)i * 2;
    float4 a = p[0], c = p[1];
    u32 o0 = (u32)f2bf(a.x) | ((u32)f2bf(a.y) << 16);
    u32 o1 = (u32)f2bf(a.z) | ((u32)f2bf(a.w) << 16);
    u32 o2 = (u32)f2bf(c.x) | ((u32)f2bf(c.y) << 16);
    u32 o3 = (u32)f2bf(c.z) | ((u32)f2bf(c.w) << 16);
    reinterpret_cast<uint4*>(out)[i] = make_uint4(o0, o1, o2, o3);
  } else {
    int i = (b - 4096) * 256 + tid;  // S*64 = 262144 threads
    int pos = i >> 6, f = i & 63;
    float inv = expf(-0.1439115683121279f * (float)f);  // 10000^(-f/64)
    float ang = (float)pos * inv;
    float s, c;
    sincosf(ang, &s, &c);
    cosT[i] = c;
    sinT[i] = s;
  }
}

// ---------------- merged weight transpose: all 4 weights in one launch ----------------
__global__ void k_transpose_all(const float* __restrict__ wq, const float* __restrict__ wk,
                                const float* __restrict__ wv, const float* __restrict__ wo,
                                u16* __restrict__ WqT, u16* __restrict__ WkT,
                                u16* __restrict__ WvT, u16* __restrict__ WoT) {
  __shared__ float t[32][33];
  int b = blockIdx.x;
  const float* W;
  u16* Wt;
  int Kd, Nd, bx, by;
  if (b < 4096) {
    W = wq; Wt = WqT; Kd = HDIM; Nd = HDIM; bx = b & 63; by = b >> 6;
  } else if (b < 5120) {
    int r = b - 4096; W = wk; Wt = WkT; Kd = HDIM; Nd = KVDIM; bx = r & 15; by = r >> 4;
  } else if (b < 6144) {
    int r = b - 5120; W = wv; Wt = WvT; Kd = HDIM; Nd = KVDIM; bx = r & 15; by = r >> 4;
  } else {
    int r = b - 6144; W = wo; Wt = WoT; Kd = HDIM; Nd = HDIM; bx = r & 63; by = r >> 6;
  }
  int tx = threadIdx.x & 31, ty = threadIdx.x >> 5;
  int n = bx * 32 + tx;
  for (int j = ty; j < 32; j += 8)
    t[j][tx] = W[(size_t)(by * 32 + j) * Nd + n];
  __syncthreads();
  int k = by * 32 + tx;
  for (int j = ty; j < 32; j += 8)
    Wt[(size_t)(bx * 32 + j) * Kd + k] = f2bf(t[tx][j]);
}

// ---------------- merged RoPE apply: Q (blocks 0..4095) + K (4096..5119) ----------------
__global__ void k_rope_all(u16* __restrict__ Qb, u16* __restrict__ Kb,
                           const float* __restrict__ cosT, const float* __restrict__ sinT) {
  int b = blockIdx.x;
  u16* X;
  int width, i;
  if (b < 4096) { X = Qb; width = HDIM; i = b * 256 + threadIdx.x; }
  else { X = Kb; width = KVDIM; i = (b - 4096) * 256 + threadIdx.x; }
  size_t idx = (size_t)i * 8;
  int row = (int)(idx / width);
  int col = (int)(idx - (size_t)row * width);
  int fi = (col & 127) >> 1;  // multiple of 4
  float4 c4 = *reinterpret_cast<const float4*>(&cosT[(row << 6) + fi]);
  float4 s4 = *reinterpret_cast<const float4*>(&sinT[(row << 6) + fi]);
  uint4 v = *reinterpret_cast<const uint4*>(&X[idx]);
  float cc[4] = {c4.x, c4.y, c4.z, c4.w};
  float ss[4] = {s4.x, s4.y, s4.z, s4.w};
  u32 w_[4] = {v.x, v.y, v.z, v.w};
  u32 r_[4];
#pragma unroll
  for (int p = 0; p < 4; ++p) {
    float x1 = bf2f((u16)(w_[p] & 0xffff));
    float x2 = bf2f((u16)(w_[p] >> 16));
    float r1 = x1 * cc[p] - x2 * ss[p];
    float r2 = x1 * ss[p] + x2 * cc[p];
    r_[p] = (u32)f2bf(r1) | ((u32)f2bf(r2) << 16);
  }
  *reinterpret_cast<uint4*>(&X[idx]) = make_uint4(r_[0], r_[1], r_[2], r_[3]);
}

// ---------------- merged QKV projection, BK=64 + source-swizzle, XCD-swizzled --------
__global__ __launch_bounds__(256) void k_gemm_qkv(
    const u16* __restrict__ A, const u16* __restrict__ WqT, const u16* __restrict__ WkT,
    const u16* __restrict__ WvT, u16* __restrict__ Qb, u16* __restrict__ Kb,
    u16* __restrict__ VTb) {
  const int Kd = HDIM, M = S_LEN;
  __shared__ __align__(16) u16 As[128 * 64];
  __shared__ __align__(16) u16 Bs[128 * 64];
  const int p = blockIdx.x;
  const int bmg = p & 7, r = p >> 3;
  const int bm = (bmg * 4 + (r & 3)) * 128;
  const int by = r >> 2;
  const u16* Bt;
  int bn, N, mode;  // mode 0: Qb, 1: Kb, 2: VTb^T
  if (by < 16) { Bt = WqT; bn = by * 128; N = HDIM; mode = 0; }
  else if (by < 20) { Bt = WkT; bn = (by - 16) * 128; N = KVDIM; mode = 1; }
  else { Bt = WvT; bn = (by - 20) * 128; N = KVDIM; mode = 2; }
  const int tid = threadIdx.x;
  const int lane = tid & 63;
  const int wid = tid >> 6;
  const int wr = (wid >> 1) * 64, wc = (wid & 1) * 64;
  const int lr = lane & 15, lhi = lane >> 4;
  f32x4 acc[4][4] = {};
  for (int k0 = 0; k0 < Kd; k0 += 64) {
#pragma unroll
    for (int it = 0; it < 4; ++it) {
      int s = it * 256 + tid;
      int row = s >> 3, c = s & 7;
      int sc = (c ^ (row & 7)) * 8;
      gload16(&A[(size_t)(bm + row) * Kd + k0 + sc], &As[s * 8]);
      gload16(&Bt[(size_t)(bn + row) * Kd + k0 + sc], &Bs[s * 8]);
    }
    __syncthreads();
#pragma unroll
    for (int kk = 0; kk < 2; ++kk) {
      bf16x8 af[4], bfr[4];
#pragma unroll
      for (int m = 0; m < 4; ++m) {
        int row = wr + m * 16 + lr;
        int rc = (kk * 4 + lhi) ^ (row & 7);
        af[m] = *reinterpret_cast<const bf16x8*>(&As[row * 64 + rc * 8]);
      }
#pragma unroll
      for (int n = 0; n < 4; ++n) {
        int row = wc + n * 16 + lr;
        int rc = (kk * 4 + lhi) ^ (row & 7);
        bfr[n] = *reinterpret_cast<const bf16x8*>(&Bs[row * 64 + rc * 8]);
      }
#pragma unroll
      for (int m = 0; m < 4; ++m)
#pragma unroll
        for (int n = 0; n < 4; ++n)
          acc[m][n] = __builtin_amdgcn_mfma_f32_16x16x32_bf16(af[m], bfr[n], acc[m][n], 0, 0, 0);
    }
    __syncthreads();
  }
#pragma unroll
  for (int m = 0; m < 4; ++m) {
    int grow0 = bm + wr + m * 16 + lhi * 4;
#pragma unroll
    for (int n = 0; n < 4; ++n) {
      int gcol = bn + wc + n * 16 + lr;
      if (mode == 2) {
        ushort4 pk;
        pk.x = f2bf(acc[m][n][0]);
        pk.y = f2bf(acc[m][n][1]);
        pk.z = f2bf(acc[m][n][2]);
        pk.w = f2bf(acc[m][n][3]);
        *reinterpret_cast<ushort4*>(&VTb[(size_t)gcol * M + grow0]) = pk;
      } else {
        u16* outp = (mode == 0) ? Qb : Kb;
#pragma unroll
        for (int r2 = 0; r2 < 4; ++r2)
          outp[(size_t)(grow0 + r2) * N + gcol] = f2bf(acc[m][n][r2]);
      }
    }
  }
}

// ---------------- out-proj GEMM, BK=64 + source-swizzle, XCD-swizzled ----------------
__global__ __launch_bounds__(256) void k_gemm_bt(
    const u16* __restrict__ A, const u16* __restrict__ Bt, float* __restrict__ Cout,
    int M, int N, int Kd) {
  __shared__ __align__(16) u16 As[128 * 64];
  __shared__ __align__(16) u16 Bs[128 * 64];
  const int p = blockIdx.x;
  const int bmg = p & 7, r = p >> 3;
  const int bm = (bmg * 4 + (r & 3)) * 128;
  const int bn = (r >> 2) * 128;
  const int tid = threadIdx.x;
  const int lane = tid & 63;
  const int wid = tid >> 6;
  const int wr = (wid >> 1) * 64, wc = (wid & 1) * 64;
  const int lr = lane & 15, lhi = lane >> 4;
  f32x4 acc[4][4] = {};
  for (int k0 = 0; k0 < Kd; k0 += 64) {
#pragma unroll
    for (int it = 0; it < 4; ++it) {
      int s = it * 256 + tid;
      int row = s >> 3, c = s & 7;
      int sc = (c ^ (row & 7)) * 8;
      gload16(&A[(size_t)(bm + row) * Kd + k0 + sc], &As[s * 8]);
      gload16(&Bt[(size_t)(bn + row) * Kd + k0 + sc], &Bs[s * 8]);
    }
    __syncthreads();
#pragma unroll
    for (int kk = 0; kk < 2; ++kk) {
      bf16x8 af[4], bfr[4];
#pragma unroll
      for (int m = 0; m < 4; ++m) {
        int row = wr + m * 16 + lr;
        int rc = (kk * 4 + lhi) ^ (row & 7);
        af[m] = *reinterpret_cast<const bf16x8*>(&As[row * 64 + rc * 8]);
      }
#pragma unroll
      for (int n = 0; n < 4; ++n) {
        int row = wc + n * 16 + lr;
        int rc = (kk * 4 + lhi) ^ (row & 7);
        bfr[n] = *reinterpret_cast<const bf16x8*>(&Bs[row * 64 + rc * 8]);
      }
#pragma unroll
      for (int m = 0; m < 4; ++m)
#pragma unroll
        for (int n = 0; n < 4; ++n)
          acc[m][n] = __builtin_amdgcn_mfma_f32_16x16x32_bf16(af[m], bfr[n], acc[m][n], 0, 0, 0);
    }
    __syncthreads();
  }
#pragma unroll
  for (int m = 0; m < 4; ++m) {
    int grow0 = bm + wr + m * 16 + lhi * 4;
#pragma unroll
    for (int n = 0; n < 4; ++n) {
      int gcol = bn + wc + n * 16 + lr;
#pragma unroll
      for (int r2 = 0; r2 < 4; ++r2)
        Cout[(size_t)(grow0 + r2) * N + gcol] = acc[m][n][r2];
    }
  }
}

// ---------------- flash attention v16: single barrier/tile via LDS double-buffer ----
// R24 structure + 2x LDS buffers. Safety: buf[j&1] was last READ at tile j-2; the
// barrier at tile j-1 separates that read from this write -> only ONE barrier
// (write->read publish) needed per tile. LDS 64KB/block, 2 blocks/CU (128<=160).
__global__ __launch_bounds__(512, 2) void k_attn(
    const u16* __restrict__ Q, const u16* __restrict__ K, const u16* __restrict__ VT,
    u16* __restrict__ PO0, u16* __restrict__ PO1, float2* __restrict__ ML) {
  __shared__ __align__(16) u16 Ks[2][64 * 128];   // [buf][kv][d], xor-swizzled
  __shared__ __align__(16) u16 Vs[2][128 * 64];   // [buf][d][kv], xor-swizzled
  int i = blockIdx.x;
  const int x = i & 7, s = i >> 3;
  const int kvh = x >> 1;
  const int kvhalf = x & 1;
  const int hp = s & 3;
  const int u = s >> 2;  // 0..15
  const int qt = (u < 8) ? u : (23 - u);  // q-tile of 256 rows
  const int h = kvh * 4 + hp;
  const int tid = threadIdx.x, lane = tid & 63, wid = tid >> 6;  // wid 0..7
  const int l31 = lane & 31, hi = lane >> 5;
  const int qw = qt * 256 + wid * 32;
  const int qglob = qw + l31;
  const float CE = 0.12751743f;   // log2(e)/sqrt(128)
  const float THR = 62.74f;       // 8/CE

  const u16* qptr = &Q[(size_t)qglob * HDIM + h * HEAD_D];
  bf16x8 qf[8];
#pragma unroll
  for (int ks = 0; ks < 8; ++ks)
    qf[ks] = *reinterpret_cast<const bf16x8*>(&qptr[ks * 16 + hi * 8]);

  f32x16 o_[4] = {};
  float m_ = -3e38f, l_ = 0.f;

  // j-invariant staging geometry (2 K-chunks + 2 V-chunks per thread)
  int kdb[2], vdb[2];
  const u16* kpb[2];
  const u16* vpb[2];
#pragma unroll
  for (int it = 0; it < 2; ++it) {
    int sI = it * 512 + tid;
    int kv = sI >> 4, c16 = sI & 15;
    int db = kv * 256 + c16 * 16;
    db ^= ((db >> 8) & 7) << 4;
    kdb[it] = db;
    kpb[it] = K + (size_t)kv * KVDIM + kvh * HEAD_D + c16 * 8;
    int d = sI >> 3, k16 = sI & 7;
    int db2 = d * 128 + k16 * 16;
    db2 ^= ((db2 >> 7) & 7) << 4;
    vdb[it] = db2;
    vpb[it] = VT + (size_t)(kvh * HEAD_D + d) * S_LEN + k16 * 8;
  }

  const int half_tiles = 2 * (qt + 1);  // 64-kv tiles per half
  const int j0 = kvhalf * half_tiles;
  const int j1 = j0 + half_tiles;
  // prefetch tile j0 (K + V)
  uint4 kreg0 = *reinterpret_cast<const uint4*>(kpb[0] + (size_t)(j0 << 6) * KVDIM);
  uint4 kreg1 = *reinterpret_cast<const uint4*>(kpb[1] + (size_t)(j0 << 6) * KVDIM);
  uint4 vreg0 = *reinterpret_cast<const uint4*>(vpb[0] + (j0 << 6));
  uint4 vreg1 = *reinterpret_cast<const uint4*>(vpb[1] + (j0 << 6));
  for (int j = j0; j < j1; ++j) {
    const int kb = j << 6;
    char* KsB = (char*)Ks[j & 1];
    char* VsB = (char*)Vs[j & 1];
    // publish prefetched K + V into buf[j&1] (last read at j-2; barrier at j-1
    // already separated that read from this write -> no pre-write barrier needed)
    *reinterpret_cast<uint4*>(KsB + kdb[0]) = kreg0;
    *reinterpret_cast<uint4*>(KsB + kdb[1]) = kreg1;
    *reinterpret_cast<uint4*>(VsB + vdb[0]) = vreg0;
    *reinterpret_cast<uint4*>(VsB + vdb[1]) = vreg1;
    __syncthreads();  // single barrier: all writes to buf[j&1] visible
    // issue K+V prefetch for tile j+1; latency hides under compute(j)
    if (j + 1 < j1) {
      const size_t koff = (size_t)((j + 1) << 6) * KVDIM;
      const int voff = (j + 1) << 6;
      kreg0 = *reinterpret_cast<const uint4*>(kpb[0] + koff);
      kreg1 = *reinterpret_cast<const uint4*>(kpb[1] + koff);
      vreg0 = *reinterpret_cast<const uint4*>(vpb[0] + voff);
      vreg1 = *reinterpret_cast<const uint4*>(vpb[1] + voff);
    }

    if (kb <= qw + 31) {  // wave-uniform participation
      f32x16 s0 = {}, s1 = {};
#pragma unroll
      for (int ks = 0; ks < 8; ++ks) {
        int db0 = l31 * 256 + ks * 32 + hi * 16;
        db0 ^= ((db0 >> 8) & 7) << 4;
        int db1 = (32 + l31) * 256 + ks * 32 + hi * 16;
        db1 ^= ((db1 >> 8) & 7) << 4;
        bf16x8 k0 = *reinterpret_cast<const bf16x8*>(KsB + db0);
        bf16x8 k1 = *reinterpret_cast<const bf16x8*>(KsB + db1);
        s0 = __builtin_amdgcn_mfma_f32_32x32x16_bf16(k0, qf[ks], s0, 0, 0, 0);
        s1 = __builtin_amdgcn_mfma_f32_32x32x16_bf16(k1, qf[ks], s1, 0, 0, 0);
      }
      if (kb + 63 > qw) {
#pragma unroll
        for (int r = 0; r < 16; ++r) {
          int kvr = kb + (r & 3) + 8 * (r >> 2) + 4 * hi;
          if (kvr > qglob) s0[r] = -1e30f;
          if (kvr + 32 > qglob) s1[r] = -1e30f;
        }
      }
      float pm = fmaxf(s0[0], s1[0]);
#pragma unroll
      for (int r = 1; r < 16; ++r) pm = fmaxf(pm, fmaxf(s0[r], s1[r]));
      pm = fmaxf(pm, __shfl_xor(pm, 32));
      if (!__all(pm <= m_ + THR)) {
        float mnew = fmaxf(m_, pm);
        float fac = exp2_fast((m_ - mnew) * CE);
        m_ = mnew;
        l_ *= fac;
#pragma unroll
        for (int dt = 0; dt < 4; ++dt)
#pragma unroll
          for (int r = 0; r < 16; ++r) o_[dt][r] *= fac;
      }
      const float mc = m_ * CE;
      float rs = 0.f;
#pragma unroll
      for (int r = 0; r < 16; ++r) {
        s0[r] = exp2_fast(__builtin_fmaf(s0[r], CE, -mc));
        s1[r] = exp2_fast(__builtin_fmaf(s1[r], CE, -mc));
        rs += s0[r] + s1[r];
      }
      rs += __shfl_xor(rs, 32);
      l_ += rs;
#pragma unroll
      for (int kvt = 0; kvt < 2; ++kvt) {
        u32 xw[8], yw[8];
#pragma unroll
        for (int gI = 0; gI < 8; ++gI) {
          float plo = kvt ? s1[2 * gI] : s0[2 * gI];
          float phi = kvt ? s1[2 * gI + 1] : s0[2 * gI + 1];
          u32 pw = cvt_pk_bf16(plo, phi);
          v2i sw = __builtin_amdgcn_permlane32_swap((int)pw, (int)pw, false, false);
          xw[gI] = (u32)sw[0];
          yw[gI] = (u32)sw[1];
        }
#pragma unroll
        for (int ksl = 0; ksl < 2; ++ksl) {
          int b = ksl * 4;
          u32 f0 = hi ? xw[b + 2] : xw[b + 0];
          u32 f1 = hi ? xw[b + 3] : xw[b + 1];
          u32 f2 = hi ? yw[b + 2] : yw[b + 0];
          u32 f3 = hi ? yw[b + 3] : yw[b + 1];
          uint4 fr = make_uint4(f0, f1, f2, f3);
          bf16x8 pf = *reinterpret_cast<bf16x8*>(&fr);
          const int kvstep = kvt * 2 + ksl;
#pragma unroll
          for (int dt = 0; dt < 4; ++dt) {
            int db = (dt * 32 + l31) * 128 + kvstep * 32 + hi * 16;
            db ^= ((db >> 7) & 7) << 4;
            bf16x8 vf = *reinterpret_cast<const bf16x8*>(VsB + db);
            o_[dt] = __builtin_amdgcn_mfma_f32_32x32x16_bf16(vf, pf, o_[dt], 0, 0, 0);
          }
        }
      }
    }
  }
  const float inv_l = (l_ > 0.f) ? (1.0f / l_) : 0.f;
  u16* PO = kvhalf ? PO1 : PO0;
  u16* optr = &PO[(size_t)qglob * HDIM + h * HEAD_D];
#pragma unroll
  for (int dt = 0; dt < 4; ++dt)
#pragma unroll
    for (int gI = 0; gI < 4; ++gI) {
      ushort4 pk;
      pk.x = f2bf(o_[dt][4 * gI + 0] * inv_l);
      pk.y = f2bf(o_[dt][4 * gI + 1] * inv_l);
      pk.z = f2bf(o_[dt][4 * gI + 2] * inv_l);
      pk.w = f2bf(o_[dt][4 * gI + 3] * inv_l);
      *reinterpret_cast<ushort4*>(&optr[dt * 32 + gI * 8 + hi * 4]) = pk;
    }
  if (hi == 0)
    ML[(size_t)kvhalf * N_HEADS * S_LEN + (size_t)h * S_LEN + qglob] =
        make_float2(m_, l_);
}

// ---------------- combine partial attention halves (element-wise) ----------------
__global__ void k_combine(const u16* __restrict__ PO0, const u16* __restrict__ PO1,
                          const float2* __restrict__ ML, u16* __restrict__ Out) {
  int i = blockIdx.x * 256 + threadIdx.x;  // S*HDIM/8 threads
  int d8 = (i & 15) * 8;
  int qh = i >> 4;
  int h = qh & 15, q = qh >> 4;
  const float CE = 0.12751743f;
  float2 ml1 = ML[(size_t)h * S_LEN + q];
  float2 ml2 = ML[(size_t)N_HEADS * S_LEN + (size_t)h * S_LEN + q];
  float m = fmaxf(ml1.x, ml2.x);
  float w1 = ml1.y * exp2_fast((ml1.x - m) * CE);
  float w2 = ml2.y * exp2_fast((ml2.x - m) * CE);
  float inv = 1.0f / (w1 + w2);
  w1 *= inv;
  w2 *= inv;
  size_t base = (size_t)q * HDIM + h * HEAD_D + d8;
  uint4 a = *reinterpret_cast<const uint4*>(&PO0[base]);
  uint4 b = *reinterpret_cast<const uint4*>(&PO1[base]);
  u32 aw[4] = {a.x, a.y, a.z, a.w}, bw[4] = {b.x, b.y, b.z, b.w};
  u32 ow[4];
#pragma unroll
  for (int p = 0; p < 4; ++p) {
    float lo = w1 * bf2f((u16)(aw[p] & 0xffff)) + w2 * bf2f((u16)(bw[p] & 0xffff));
    float hi2 = w1 * bf2f((u16)(aw[p] >> 16)) + w2 * bf2f((u16)(bw[p] >> 16));
    ow[p] = (u32)f2bf(lo) | ((u32)f2bf(hi2) << 16);
  }
  *reinterpret_cast<uint4*>(&Out[base]) = make_uint4(ow[0], ow[1], ow[2], ow[3]);
}

extern "C" void kernel_launch(void* const* d_in, const int* in_sizes, int n_in,
                              void* d_out, int out_size, void* d_ws, size_t ws_size,
                              hipStream_t stream) {
  const float* hs = (const float*)d_in[0];
  const float* wq = (const float*)d_in[1];
  const float* wk = (const float*)d_in[2];
  const float* wv = (const float*)d_in[3];
  const float* wo = (const float*)d_in[4];

  char* ws = (char*)d_ws;
  size_t off = 0;
  auto alloc = [&](size_t bytes) {
    void* p = ws + off;
    off += (bytes + 255) & ~(size_t)255;
    return p;
  };
  u16* Xb = (u16*)alloc((size_t)S_LEN * HDIM * 2);
  u16* WqT = (u16*)alloc((size_t)HDIM * HDIM * 2);
  u16* WkT = (u16*)alloc((size_t)KVDIM * HDIM * 2);
  u16* WvT = (u16*)alloc((size_t)KVDIM * HDIM * 2);
  u16* WoT = (u16*)alloc((size_t)HDIM * HDIM * 2);
  u16* Qb = (u16*)alloc((size_t)S_LEN * HDIM * 2);
  u16* Kb = (u16*)alloc((size_t)S_LEN * KVDIM * 2);
  u16* VTb = (u16*)alloc((size_t)KVDIM * S_LEN * 2);  // V^T [512][4096]
  u16* Ab = (u16*)alloc((size_t)S_LEN * HDIM * 2);
  float* cosT = (float*)alloc((size_t)S_LEN * 64 * 4);
  float* sinT = (float*)alloc((size_t)S_LEN * 64 * 4);
  if (off > ws_size) return;  // workspace too small; avoid OOB

  // dead-buffer reuse after k_gemm_qkv: PO1 <- Xb, ML <- WqT; PO0 = Ab
  u16* PO0 = Ab;
  u16* PO1 = Xb;
  float2* ML = (float2*)WqT;

  // 1. cast hidden + rope table (merged; 4096 + 1024 blocks)
  k_prep<<<dim3(5120), dim3(256), 0, stream>>>(hs, Xb, cosT, sinT);
  // 2. all weight transposes (merged)
  k_transpose_all<<<dim3(10240), dim3(256), 0, stream>>>(wq, wk, wv, wo, WqT, WkT, WvT, WoT);
  // 3. merged QKV projection (BK=64, XCD-swizzled, V written transposed)
  k_gemm_qkv<<<dim3(768), dim3(256), 0, stream>>>(Xb, WqT, WkT, WvT, Qb, Kb, VTb);
  // 4. rope on Q + K (merged)
  k_rope_all<<<dim3(5120), dim3(256), 0, stream>>>(Qb, Kb, cosT, sinT);
  // 5. attention: QBLK=256, KV-split x2, XCD-local KV, K+V prefetch, 1 barrier/tile
  k_attn<<<dim3(512), dim3(512), 0, stream>>>(Qb, Kb, VTb, PO0, PO1, ML);
  k_combine<<<dim3(4096), dim3(256), 0, stream>>>(PO0, PO1, ML, Ab);
  // 6. output projection -> f32 (BK=64, XCD-swizzled)
  k_gemm_bt<<<dim3(512), dim3(256), 0, stream>>>(Ab, WoT, (float*)d_out, S_LEN, HDIM, HDIM);
}

// Round 26
// 253.090 us; speedup vs baseline: 1.1173x; 1.1173x over previous
//
#include <hip/hip_runtime.h>

typedef unsigned short u16;
typedef unsigned int u32;
typedef __bf16 bf16x8 __attribute__((ext_vector_type(8)));
typedef float f32x4 __attribute__((ext_vector_type(4)));
typedef float f32x16 __attribute__((ext_vector_type(16)));
typedef int v2i __attribute__((ext_vector_type(2)));

#define S_LEN 4096
#define HDIM 2048
#define KVDIM 512
#define N_HEADS 16
#define HEAD_D 128

__device__ __forceinline__ u16 f2bf(float f) {
  u32 u = __float_as_uint(f);
  u32 r = (u + 0x7FFFu + ((u >> 16) & 1u)) >> 16;
  return (u16)r;
}
__device__ __forceinline__ float bf2f(u16 h) {
  return __uint_as_float(((u32)h) << 16);
}
__device__ __forceinline__ float exp2_fast(float x) {
  float r;
  asm("v_exp_f32 %0, %1" : "=v"(r) : "v"(x));
  return r;
}
__device__ __forceinline__ u32 cvt_pk_bf16(float lo, float hi) {
  u32 r;
  asm("v_cvt_pk_bf16_f32 %0, %1, %2" : "=v"(r) : "v"(lo), "v"(hi));
  return r;
}
__device__ __forceinline__ void gload16(const u16* g, const u16* l) {
  __builtin_amdgcn_global_load_lds(
      (const __attribute__((address_space(1))) void*)g,
      (__attribute__((address_space(3))) void*)l, 16, 0, 0);
}

// ---------------- prep: f32->bf16 cast (blocks 0..4095) + rope table (4096..5119) ----
__global__ void k_prep(const float* __restrict__ in, u16* __restrict__ out,
                       float* __restrict__ cosT, float* __restrict__ sinT) {
  int b = blockIdx.x;
  int tid = threadIdx.x;
  if (b < 4096) {
    int i = b * 256 + tid;  // S*HDIM/8 = 1048576 threads
    const float4* p = reinterpret_cast<const float4*>(in) + (size_t)i * 2;
    float4 a = p[0], c = p[1];
    u32 o0 = (u32)f2bf(a.x) | ((u32)f2bf(a.y) << 16);
    u32 o1 = (u32)f2bf(a.z) | ((u32)f2bf(a.w) << 16);
    u32 o2 = (u32)f2bf(c.x) | ((u32)f2bf(c.y) << 16);
    u32 o3 = (u32)f2bf(c.z) | ((u32)f2bf(c.w) << 16);
    reinterpret_cast<uint4*>(out)[i] = make_uint4(o0, o1, o2, o3);
  } else {
    int i = (b - 4096) * 256 + tid;  // S*64 = 262144 threads
    int pos = i >> 6, f = i & 63;
    float inv = expf(-0.1439115683121279f * (float)f);  // 10000^(-f/64)
    float ang = (float)pos * inv;
    float s, c;
    sincosf(ang, &s, &c);
    cosT[i] = c;
    sinT[i] = s;
  }
}

// ---------------- merged weight transpose: all 4 weights in one launch ----------------
__global__ void k_transpose_all(const float* __restrict__ wq, const float* __restrict__ wk,
                                const float* __restrict__ wv, const float* __restrict__ wo,
                                u16* __restrict__ WqT, u16* __restrict__ WkT,
                                u16* __restrict__ WvT, u16* __restrict__ WoT) {
  __shared__ float t[32][33];
  int b = blockIdx.x;
  const float* W;
  u16* Wt;
  int Kd, Nd, bx, by;
  if (b < 4096) {
    W = wq; Wt = WqT; Kd = HDIM; Nd = HDIM; bx = b & 63; by = b >> 6;
  } else if (b < 5120) {
    int r = b - 4096; W = wk; Wt = WkT; Kd = HDIM; Nd = KVDIM; bx = r & 15; by = r >> 4;
  } else if (b < 6144) {
    int r = b - 5120; W = wv; Wt = WvT; Kd = HDIM; Nd = KVDIM; bx = r & 15; by = r >> 4;
  } else {
    int r = b - 6144; W = wo; Wt = WoT; Kd = HDIM; Nd = HDIM; bx = r & 63; by = r >> 6;
  }
  int tx = threadIdx.x & 31, ty = threadIdx.x >> 5;
  int n = bx * 32 + tx;
  for (int j = ty; j < 32; j += 8)
    t[j][tx] = W[(size_t)(by * 32 + j) * Nd + n];
  __syncthreads();
  int k = by * 32 + tx;
  for (int j = ty; j < 32; j += 8)
    Wt[(size_t)(bx * 32 + j) * Kd + k] = f2bf(t[tx][j]);
}

// ---------------- merged RoPE apply: Q (blocks 0..4095) + K (4096..5119) ----------------
__global__ void k_rope_all(u16* __restrict__ Qb, u16* __restrict__ Kb,
                           const float* __restrict__ cosT, const float* __restrict__ sinT) {
  int b = blockIdx.x;
  u16* X;
  int width, i;
  if (b < 4096) { X = Qb; width = HDIM; i = b * 256 + threadIdx.x; }
  else { X = Kb; width = KVDIM; i = (b - 4096) * 256 + threadIdx.x; }
  size_t idx = (size_t)i * 8;
  int row = (int)(idx / width);
  int col = (int)(idx - (size_t)row * width);
  int fi = (col & 127) >> 1;  // multiple of 4
  float4 c4 = *reinterpret_cast<const float4*>(&cosT[(row << 6) + fi]);
  float4 s4 = *reinterpret_cast<const float4*>(&sinT[(row << 6) + fi]);
  uint4 v = *reinterpret_cast<const uint4*>(&X[idx]);
  float cc[4] = {c4.x, c4.y, c4.z, c4.w};
  float ss[4] = {s4.x, s4.y, s4.z, s4.w};
  u32 w_[4] = {v.x, v.y, v.z, v.w};
  u32 r_[4];
#pragma unroll
  for (int p = 0; p < 4; ++p) {
    float x1 = bf2f((u16)(w_[p] & 0xffff));
    float x2 = bf2f((u16)(w_[p] >> 16));
    float r1 = x1 * cc[p] - x2 * ss[p];
    float r2 = x1 * ss[p] + x2 * cc[p];
    r_[p] = (u32)f2bf(r1) | ((u32)f2bf(r2) << 16);
  }
  *reinterpret_cast<uint4*>(&X[idx]) = make_uint4(r_[0], r_[1], r_[2], r_[3]);
}

// ---------------- merged QKV projection, BK=64 + source-swizzle, XCD-swizzled --------
__global__ __launch_bounds__(256) void k_gemm_qkv(
    const u16* __restrict__ A, const u16* __restrict__ WqT, const u16* __restrict__ WkT,
    const u16* __restrict__ WvT, u16* __restrict__ Qb, u16* __restrict__ Kb,
    u16* __restrict__ VTb) {
  const int Kd = HDIM, M = S_LEN;
  __shared__ __align__(16) u16 As[128 * 64];
  __shared__ __align__(16) u16 Bs[128 * 64];
  const int p = blockIdx.x;
  const int bmg = p & 7, r = p >> 3;
  const int bm = (bmg * 4 + (r & 3)) * 128;
  const int by = r >> 2;
  const u16* Bt;
  int bn, N, mode;  // mode 0: Qb, 1: Kb, 2: VTb^T
  if (by < 16) { Bt = WqT; bn = by * 128; N = HDIM; mode = 0; }
  else if (by < 20) { Bt = WkT; bn = (by - 16) * 128; N = KVDIM; mode = 1; }
  else { Bt = WvT; bn = (by - 20) * 128; N = KVDIM; mode = 2; }
  const int tid = threadIdx.x;
  const int lane = tid & 63;
  const int wid = tid >> 6;
  const int wr = (wid >> 1) * 64, wc = (wid & 1) * 64;
  const int lr = lane & 15, lhi = lane >> 4;
  f32x4 acc[4][4] = {};
  for (int k0 = 0; k0 < Kd; k0 += 64) {
#pragma unroll
    for (int it = 0; it < 4; ++it) {
      int s = it * 256 + tid;
      int row = s >> 3, c = s & 7;
      int sc = (c ^ (row & 7)) * 8;
      gload16(&A[(size_t)(bm + row) * Kd + k0 + sc], &As[s * 8]);
      gload16(&Bt[(size_t)(bn + row) * Kd + k0 + sc], &Bs[s * 8]);
    }
    __syncthreads();
#pragma unroll
    for (int kk = 0; kk < 2; ++kk) {
      bf16x8 af[4], bfr[4];
#pragma unroll
      for (int m = 0; m < 4; ++m) {
        int row = wr + m * 16 + lr;
        int rc = (kk * 4 + lhi) ^ (row & 7);
        af[m] = *reinterpret_cast<const bf16x8*>(&As[row * 64 + rc * 8]);
      }
#pragma unroll
      for (int n = 0; n < 4; ++n) {
        int row = wc + n * 16 + lr;
        int rc = (kk * 4 + lhi) ^ (row & 7);
        bfr[n] = *reinterpret_cast<const bf16x8*>(&Bs[row * 64 + rc * 8]);
      }
#pragma unroll
      for (int m = 0; m < 4; ++m)
#pragma unroll
        for (int n = 0; n < 4; ++n)
          acc[m][n] = __builtin_amdgcn_mfma_f32_16x16x32_bf16(af[m], bfr[n], acc[m][n], 0, 0, 0);
    }
    __syncthreads();
  }
#pragma unroll
  for (int m = 0; m < 4; ++m) {
    int grow0 = bm + wr + m * 16 + lhi * 4;
#pragma unroll
    for (int n = 0; n < 4; ++n) {
      int gcol = bn + wc + n * 16 + lr;
      if (mode == 2) {
        ushort4 pk;
        pk.x = f2bf(acc[m][n][0]);
        pk.y = f2bf(acc[m][n][1]);
        pk.z = f2bf(acc[m][n][2]);
        pk.w = f2bf(acc[m][n][3]);
        *reinterpret_cast<ushort4*>(&VTb[(size_t)gcol * M + grow0]) = pk;
      } else {
        u16* outp = (mode == 0) ? Qb : Kb;
#pragma unroll
        for (int r2 = 0; r2 < 4; ++r2)
          outp[(size_t)(grow0 + r2) * N + gcol] = f2bf(acc[m][n][r2]);
      }
    }
  }
}

// ---------------- out-proj GEMM, BK=64 + source-swizzle, XCD-swizzled ----------------
__global__ __launch_bounds__(256) void k_gemm_bt(
    const u16* __restrict__ A, const u16* __restrict__ Bt, float* __restrict__ Cout,
    int M, int N, int Kd) {
  __shared__ __align__(16) u16 As[128 * 64];
  __shared__ __align__(16) u16 Bs[128 * 64];
  const int p = blockIdx.x;
  const int bmg = p & 7, r = p >> 3;
  const int bm = (bmg * 4 + (r & 3)) * 128;
  const int bn = (r >> 2) * 128;
  const int tid = threadIdx.x;
  const int lane = tid & 63;
  const int wid = tid >> 6;
  const int wr = (wid >> 1) * 64, wc = (wid & 1) * 64;
  const int lr = lane & 15, lhi = lane >> 4;
  f32x4 acc[4][4] = {};
  for (int k0 = 0; k0 < Kd; k0 += 64) {
#pragma unroll
    for (int it = 0; it < 4; ++it) {
      int s = it * 256 + tid;
      int row = s >> 3, c = s & 7;
      int sc = (c ^ (row & 7)) * 8;
      gload16(&A[(size_t)(bm + row) * Kd + k0 + sc], &As[s * 8]);
      gload16(&Bt[(size_t)(bn + row) * Kd + k0 + sc], &Bs[s * 8]);
    }
    __syncthreads();
#pragma unroll
    for (int kk = 0; kk < 2; ++kk) {
      bf16x8 af[4], bfr[4];
#pragma unroll
      for (int m = 0; m < 4; ++m) {
        int row = wr + m * 16 + lr;
        int rc = (kk * 4 + lhi) ^ (row & 7);
        af[m] = *reinterpret_cast<const bf16x8*>(&As[row * 64 + rc * 8]);
      }
#pragma unroll
      for (int n = 0; n < 4; ++n) {
        int row = wc + n * 16 + lr;
        int rc = (kk * 4 + lhi) ^ (row & 7);
        bfr[n] = *reinterpret_cast<const bf16x8*>(&Bs[row * 64 + rc * 8]);
      }
#pragma unroll
      for (int m = 0; m < 4; ++m)
#pragma unroll
        for (int n = 0; n < 4; ++n)
          acc[m][n] = __builtin_amdgcn_mfma_f32_16x16x32_bf16(af[m], bfr[n], acc[m][n], 0, 0, 0);
    }
    __syncthreads();
  }
#pragma unroll
  for (int m = 0; m < 4; ++m) {
    int grow0 = bm + wr + m * 16 + lhi * 4;
#pragma unroll
    for (int n = 0; n < 4; ++n) {
      int gcol = bn + wc + n * 16 + lr;
#pragma unroll
      for (int r2 = 0; r2 < 4; ++r2)
        Cout[(size_t)(grow0 + r2) * N + gcol] = acc[m][n][r2];
    }
  }
}

// ---------------- flash attention v15 (R24-verified): QBLK=256 + K&V reg prefetch ----
// Two barriers per tile, single LDS buffer (structural local optimum: dbuf/
// single-barrier, KVBLK=128, setprio, tree-reduce all regressed it).
__global__ __launch_bounds__(512, 2) void k_attn(
    const u16* __restrict__ Q, const u16* __restrict__ K, const u16* __restrict__ VT,
    u16* __restrict__ PO0, u16* __restrict__ PO1, float2* __restrict__ ML) {
  __shared__ __align__(16) u16 Ks[64 * 128];   // [kv][d], xor-swizzled, 16KB
  __shared__ __align__(16) u16 Vs[128 * 64];   // [d][kv], xor-swizzled, 16KB
  int i = blockIdx.x;
  const int x = i & 7, s = i >> 3;
  const int kvh = x >> 1;
  const int kvhalf = x & 1;
  const int hp = s & 3;
  const int u = s >> 2;  // 0..15
  const int qt = (u < 8) ? u : (23 - u);  // q-tile of 256 rows
  const int h = kvh * 4 + hp;
  const int tid = threadIdx.x, lane = tid & 63, wid = tid >> 6;  // wid 0..7
  const int l31 = lane & 31, hi = lane >> 5;
  const int qw = qt * 256 + wid * 32;
  const int qglob = qw + l31;
  const float CE = 0.12751743f;   // log2(e)/sqrt(128)
  const float THR = 62.74f;       // 8/CE

  const u16* qptr = &Q[(size_t)qglob * HDIM + h * HEAD_D];
  bf16x8 qf[8];
#pragma unroll
  for (int ks = 0; ks < 8; ++ks)
    qf[ks] = *reinterpret_cast<const bf16x8*>(&qptr[ks * 16 + hi * 8]);

  f32x16 o_[4] = {};
  float m_ = -3e38f, l_ = 0.f;
  char* KsB = (char*)Ks;
  char* VsB = (char*)Vs;

  // j-invariant staging geometry (2 K-chunks + 2 V-chunks per thread)
  int kdb[2], vdb[2];
  const u16* kpb[2];
  const u16* vpb[2];
#pragma unroll
  for (int it = 0; it < 2; ++it) {
    int sI = it * 512 + tid;
    int kv = sI >> 4, c16 = sI & 15;
    int db = kv * 256 + c16 * 16;
    db ^= ((db >> 8) & 7) << 4;
    kdb[it] = db;
    kpb[it] = K + (size_t)kv * KVDIM + kvh * HEAD_D + c16 * 8;
    int d = sI >> 3, k16 = sI & 7;
    int db2 = d * 128 + k16 * 16;
    db2 ^= ((db2 >> 7) & 7) << 4;
    vdb[it] = db2;
    vpb[it] = VT + (size_t)(kvh * HEAD_D + d) * S_LEN + k16 * 8;
  }

  const int half_tiles = 2 * (qt + 1);  // 64-kv tiles per half
  const int j0 = kvhalf * half_tiles;
  const int j1 = j0 + half_tiles;
  // prefetch tile j0 (K + V)
  uint4 kreg0 = *reinterpret_cast<const uint4*>(kpb[0] + (size_t)(j0 << 6) * KVDIM);
  uint4 kreg1 = *reinterpret_cast<const uint4*>(kpb[1] + (size_t)(j0 << 6) * KVDIM);
  uint4 vreg0 = *reinterpret_cast<const uint4*>(vpb[0] + (j0 << 6));
  uint4 vreg1 = *reinterpret_cast<const uint4*>(vpb[1] + (j0 << 6));
  for (int j = j0; j < j1; ++j) {
    const int kb = j << 6;
    __syncthreads();
    // publish prefetched K + V tiles (swizzled LDS writes only)
    *reinterpret_cast<uint4*>(KsB + kdb[0]) = kreg0;
    *reinterpret_cast<uint4*>(KsB + kdb[1]) = kreg1;
    *reinterpret_cast<uint4*>(VsB + vdb[0]) = vreg0;
    *reinterpret_cast<uint4*>(VsB + vdb[1]) = vreg1;
    __syncthreads();
    // issue K+V prefetch for tile j+1; latency hides under compute(j)
    if (j + 1 < j1) {
      const size_t koff = (size_t)((j + 1) << 6) * KVDIM;
      const int voff = (j + 1) << 6;
      kreg0 = *reinterpret_cast<const uint4*>(kpb[0] + koff);
      kreg1 = *reinterpret_cast<const uint4*>(kpb[1] + koff);
      vreg0 = *reinterpret_cast<const uint4*>(vpb[0] + voff);
      vreg1 = *reinterpret_cast<const uint4*>(vpb[1] + voff);
    }

    if (kb <= qw + 31) {  // wave-uniform participation
      f32x16 s0 = {}, s1 = {};
#pragma unroll
      for (int ks = 0; ks < 8; ++ks) {
        int db0 = l31 * 256 + ks * 32 + hi * 16;
        db0 ^= ((db0 >> 8) & 7) << 4;
        int db1 = (32 + l31) * 256 + ks * 32 + hi * 16;
        db1 ^= ((db1 >> 8) & 7) << 4;
        bf16x8 k0 = *reinterpret_cast<const bf16x8*>(KsB + db0);
        bf16x8 k1 = *reinterpret_cast<const bf16x8*>(KsB + db1);
        s0 = __builtin_amdgcn_mfma_f32_32x32x16_bf16(k0, qf[ks], s0, 0, 0, 0);
        s1 = __builtin_amdgcn_mfma_f32_32x32x16_bf16(k1, qf[ks], s1, 0, 0, 0);
      }
      if (kb + 63 > qw) {
#pragma unroll
        for (int r = 0; r < 16; ++r) {
          int kvr = kb + (r & 3) + 8 * (r >> 2) + 4 * hi;
          if (kvr > qglob) s0[r] = -1e30f;
          if (kvr + 32 > qglob) s1[r] = -1e30f;
        }
      }
      float pm = fmaxf(s0[0], s1[0]);
#pragma unroll
      for (int r = 1; r < 16; ++r) pm = fmaxf(pm, fmaxf(s0[r], s1[r]));
      pm = fmaxf(pm, __shfl_xor(pm, 32));
      if (!__all(pm <= m_ + THR)) {
        float mnew = fmaxf(m_, pm);
        float fac = exp2_fast((m_ - mnew) * CE);
        m_ = mnew;
        l_ *= fac;
#pragma unroll
        for (int dt = 0; dt < 4; ++dt)
#pragma unroll
          for (int r = 0; r < 16; ++r) o_[dt][r] *= fac;
      }
      const float mc = m_ * CE;
      float rs = 0.f;
#pragma unroll
      for (int r = 0; r < 16; ++r) {
        s0[r] = exp2_fast(__builtin_fmaf(s0[r], CE, -mc));
        s1[r] = exp2_fast(__builtin_fmaf(s1[r], CE, -mc));
        rs += s0[r] + s1[r];
      }
      rs += __shfl_xor(rs, 32);
      l_ += rs;
#pragma unroll
      for (int kvt = 0; kvt < 2; ++kvt) {
        u32 xw[8], yw[8];
#pragma unroll
        for (int gI = 0; gI < 8; ++gI) {
          float plo = kvt ? s1[2 * gI] : s0[2 * gI];
          float phi = kvt ? s1[2 * gI + 1] : s0[2 * gI + 1];
          u32 pw = cvt_pk_bf16(plo, phi);
          v2i sw = __builtin_amdgcn_permlane32_swap((int)pw, (int)pw, false, false);
          xw[gI] = (u32)sw[0];
          yw[gI] = (u32)sw[1];
        }
#pragma unroll
        for (int ksl = 0; ksl < 2; ++ksl) {
          int b = ksl * 4;
          u32 f0 = hi ? xw[b + 2] : xw[b + 0];
          u32 f1 = hi ? xw[b + 3] : xw[b + 1];
          u32 f2 = hi ? yw[b + 2] : yw[b + 0];
          u32 f3 = hi ? yw[b + 3] : yw[b + 1];
          uint4 fr = make_uint4(f0, f1, f2, f3);
          bf16x8 pf = *reinterpret_cast<bf16x8*>(&fr);
          const int kvstep = kvt * 2 + ksl;
#pragma unroll
          for (int dt = 0; dt < 4; ++dt) {
            int db = (dt * 32 + l31) * 128 + kvstep * 32 + hi * 16;
            db ^= ((db >> 7) & 7) << 4;
            bf16x8 vf = *reinterpret_cast<const bf16x8*>(VsB + db);
            o_[dt] = __builtin_amdgcn_mfma_f32_32x32x16_bf16(vf, pf, o_[dt], 0, 0, 0);
          }
        }
      }
    }
  }
  const float inv_l = (l_ > 0.f) ? (1.0f / l_) : 0.f;
  u16* PO = kvhalf ? PO1 : PO0;
  u16* optr = &PO[(size_t)qglob * HDIM + h * HEAD_D];
#pragma unroll
  for (int dt = 0; dt < 4; ++dt)
#pragma unroll
    for (int gI = 0; gI < 4; ++gI) {
      ushort4 pk;
      pk.x = f2bf(o_[dt][4 * gI + 0] * inv_l);
      pk.y = f2bf(o_[dt][4 * gI + 1] * inv_l);
      pk.z = f2bf(o_[dt][4 * gI + 2] * inv_l);
      pk.w = f2bf(o_[dt][4 * gI + 3] * inv_l);
      *reinterpret_cast<ushort4*>(&optr[dt * 32 + gI * 8 + hi * 4]) = pk;
    }
  if (hi == 0)
    ML[(size_t)kvhalf * N_HEADS * S_LEN + (size_t)h * S_LEN + qglob] =
        make_float2(m_, l_);
}

// ---------------- combine partial attention halves (element-wise) ----------------
__global__ void k_combine(const u16* __restrict__ PO0, const u16* __restrict__ PO1,
                          const float2* __restrict__ ML, u16* __restrict__ Out) {
  int i = blockIdx.x * 256 + threadIdx.x;  // S*HDIM/8 threads
  int d8 = (i & 15) * 8;
  int qh = i >> 4;
  int h = qh & 15, q = qh >> 4;
  const float CE = 0.12751743f;
  float2 ml1 = ML[(size_t)h * S_LEN + q];
  float2 ml2 = ML[(size_t)N_HEADS * S_LEN + (size_t)h * S_LEN + q];
  float m = fmaxf(ml1.x, ml2.x);
  float w1 = ml1.y * exp2_fast((ml1.x - m) * CE);
  float w2 = ml2.y * exp2_fast((ml2.x - m) * CE);
  float inv = 1.0f / (w1 + w2);
  w1 *= inv;
  w2 *= inv;
  size_t base = (size_t)q * HDIM + h * HEAD_D + d8;
  uint4 a = *reinterpret_cast<const uint4*>(&PO0[base]);
  uint4 b = *reinterpret_cast<const uint4*>(&PO1[base]);
  u32 aw[4] = {a.x, a.y, a.z, a.w}, bw[4] = {b.x, b.y, b.z, b.w};
  u32 ow[4];
#pragma unroll
  for (int p = 0; p < 4; ++p) {
    float lo = w1 * bf2f((u16)(aw[p] & 0xffff)) + w2 * bf2f((u16)(bw[p] & 0xffff));
    float hi2 = w1 * bf2f((u16)(aw[p] >> 16)) + w2 * bf2f((u16)(bw[p] >> 16));
    ow[p] = (u32)f2bf(lo) | ((u32)f2bf(hi2) << 16);
  }
  *reinterpret_cast<uint4*>(&Out[base]) = make_uint4(ow[0], ow[1], ow[2], ow[3]);
}

extern "C" void kernel_launch(void* const* d_in, const int* in_sizes, int n_in,
                              void* d_out, int out_size, void* d_ws, size_t ws_size,
                              hipStream_t stream) {
  const float* hs = (const float*)d_in[0];
  const float* wq = (const float*)d_in[1];
  const float* wk = (const float*)d_in[2];
  const float* wv = (const float*)d_in[3];
  const float* wo = (const float*)d_in[4];

  char* ws = (char*)d_ws;
  size_t off = 0;
  auto alloc = [&](size_t bytes) {
    void* p = ws + off;
    off += (bytes + 255) & ~(size_t)255;
    return p;
  };
  u16* Xb = (u16*)alloc((size_t)S_LEN * HDIM * 2);
  u16* WqT = (u16*)alloc((size_t)HDIM * HDIM * 2);
  u16* WkT = (u16*)alloc((size_t)KVDIM * HDIM * 2);
  u16* WvT = (u16*)alloc((size_t)KVDIM * HDIM * 2);
  u16* WoT = (u16*)alloc((size_t)HDIM * HDIM * 2);
  u16* Qb = (u16*)alloc((size_t)S_LEN * HDIM * 2);
  u16* Kb = (u16*)alloc((size_t)S_LEN * KVDIM * 2);
  u16* VTb = (u16*)alloc((size_t)KVDIM * S_LEN * 2);  // V^T [512][4096]
  u16* Ab = (u16*)alloc((size_t)S_LEN * HDIM * 2);
  float* cosT = (float*)alloc((size_t)S_LEN * 64 * 4);
  float* sinT = (float*)alloc((size_t)S_LEN * 64 * 4);
  if (off > ws_size) return;  // workspace too small; avoid OOB

  // dead-buffer reuse after k_gemm_qkv: PO1 <- Xb, ML <- WqT; PO0 = Ab
  u16* PO0 = Ab;
  u16* PO1 = Xb;
  float2* ML = (float2*)WqT;

  // 1. cast hidden + rope table (merged; 4096 + 1024 blocks)
  k_prep<<<dim3(5120), dim3(256), 0, stream>>>(hs, Xb, cosT, sinT);
  // 2. all weight transposes (merged)
  k_transpose_all<<<dim3(10240), dim3(256), 0, stream>>>(wq, wk, wv, wo, WqT, WkT, WvT, WoT);
  // 3. merged QKV projection (BK=64, XCD-swizzled, V written transposed)
  k_gemm_qkv<<<dim3(768), dim3(256), 0, stream>>>(Xb, WqT, WkT, WvT, Qb, Kb, VTb);
  // 4. rope on Q + K (merged)
  k_rope_all<<<dim3(5120), dim3(256), 0, stream>>>(Qb, Kb, cosT, sinT);
  // 5. attention: QBLK=256, KV-split x2, XCD-local KV, K+V reg prefetch + combine
  k_attn<<<dim3(512), dim3(512), 0, stream>>>(Qb, Kb, VTb, PO0, PO1, ML);
  k_combine<<<dim3(4096), dim3(256), 0, stream>>>(PO0, PO1, ML, Ab);
  // 6. output projection -> f32 (BK=64, XCD-swizzled)
  k_gemm_bt<<<dim3(512), dim3(256), 0, stream>>>(Ab, WoT, (float*)d_out, S_LEN, HDIM, HDIM);
}